// Round 10
// baseline (210.863 us; speedup 1.0000x reference)
//
#include <hip/hip_runtime.h>
#include <hip/hip_bf16.h>

// B=2, L=2048, D=1024, H=16, HD=64.  M = B*L = 4096, K = D = 1024.
// ws (bytes):
//   qb   @ 0MB   bf16 [32][2048][64]   (Q pre-scaled by SM_SCALE)
//   kb   @ 8MB   bf16 [32][2048][64]
//   vtb  @16MB   bf16 [32][64][2048]   (V transposed)
//   ab   @24MB   bf16 [4096][1024]     (attn concat out)
//   embb @32MB   bf16 [4096][1024]     (also ablation dummy-out region)
//   wqt  @40MB   bf16 [48][64][1024]   (wqt/wkt/wvt contiguous, 2MB each)
//   wot  @46MB   bf16 [1024][1024]     (Wo transposed)

#define GM 4096
#define GK 1024
#define GL 2048
#define GH 16

typedef __attribute__((ext_vector_type(8))) short bf16x8;
typedef __attribute__((ext_vector_type(4))) float f32x4;
typedef __attribute__((ext_vector_type(16))) float f32x16;
typedef unsigned short u16;

__device__ __forceinline__ u16 bfu(float x) {
    __hip_bfloat16 h = __float2bfloat16(x);
    return *reinterpret_cast<u16*>(&h);
}
__device__ __forceinline__ unsigned pack_bf16(float a, float b) {
    return ((unsigned)bfu(b) << 16) | bfu(a);
}
// truncation-pack two f32 -> {bf16(a) lo, bf16(b) hi} in one v_perm_b32
__device__ __forceinline__ unsigned pack_trunc(float a, float b) {
    return __builtin_amdgcn_perm(__float_as_uint(b), __float_as_uint(a), 0x07060302u);
}
__device__ __forceinline__ void gl_lds16(const void* g, void* l) {
    __builtin_amdgcn_global_load_lds(
        (__attribute__((address_space(1))) void*)(g),
        (__attribute__((address_space(3))) void*)(l),
        16, 0, 0);
}
__device__ __forceinline__ float fexp2(float x) {
#if __has_builtin(__builtin_amdgcn_exp2f)
    return __builtin_amdgcn_exp2f(x);
#else
    return __expf(x * 0.6931471805599453f);
#endif
}
// k-row staging permutation: tile row c holds global k-row sig5(c) (within 32).
__device__ __forceinline__ int sig5(int c) {
    return (c & 3) | (((c >> 3) & 1) << 2) | (((c >> 2) & 1) << 3) | (c & 16);
}

// 0.125 (1/sqrt(64)) folded with log2(e): softmax done in exp2 domain.
#define SM_SCALE 0.1803368801111204f
#define RESCALE_THR 8.0f

// ---------------------------------------------------------------------------
// fp32 -> bf16 cast, 8 elements/thread.
// ---------------------------------------------------------------------------
__global__ __launch_bounds__(256) void cast_bf16(
    const float* __restrict__ src, u16* __restrict__ dst, int n8)
{
    int i = blockIdx.x * 256 + threadIdx.x;
    if (i >= n8) return;
    float4 v0 = reinterpret_cast<const float4*>(src)[i * 2];
    float4 v1 = reinterpret_cast<const float4*>(src)[i * 2 + 1];
    uint4 o;
    o.x = pack_bf16(v0.x, v0.y);
    o.y = pack_bf16(v0.z, v0.w);
    o.z = pack_bf16(v1.x, v1.y);
    o.w = pack_bf16(v1.z, v1.w);
    reinterpret_cast<uint4*>(dst)[i] = o;
}

// ---------------------------------------------------------------------------
// Fused Wq/Wk/Wv transpose+convert: z in [0,48) -> head (z&15) of proj (z>>4).
// ---------------------------------------------------------------------------
__global__ __launch_bounds__(256) void transpose_qkv(
    const float* __restrict__ Wq, const float* __restrict__ Wk,
    const float* __restrict__ Wv, u16* __restrict__ dst)
{
    __shared__ float T[64][65];
    const int t = threadIdx.x;
    const int z = blockIdx.z;
    const int r0 = blockIdx.x * 64;
    const float* s = (z < 16 ? Wq : (z < 32 ? Wk : Wv)) + (size_t)(z & 15) * 65536;
    u16* d = dst + (size_t)z * 65536;
#pragma unroll
    for (int i = 0; i < 4; ++i) {
        int idx = i * 256 + t;
        int row = idx >> 4, col = (idx & 15) * 4;
        float4 v = *reinterpret_cast<const float4*>(&s[(size_t)(r0 + row) * 64 + col]);
        T[row][col] = v.x; T[row][col + 1] = v.y;
        T[row][col + 2] = v.z; T[row][col + 3] = v.w;
    }
    __syncthreads();
#pragma unroll
    for (int i = 0; i < 4; ++i) {
        int idx = i * 256 + t;
        int oc = idx >> 4, ok = (idx & 15) * 4;
        ushort4 o;
        o.x = bfu(T[ok][oc]);     o.y = bfu(T[ok + 1][oc]);
        o.z = bfu(T[ok + 2][oc]); o.w = bfu(T[ok + 3][oc]);
        *reinterpret_cast<ushort4*>(&d[(size_t)oc * 1024 + r0 + ok]) = o;
    }
}

// ---------------------------------------------------------------------------
// Generic transpose+convert (for Wo): src fp32 [R][C] -> dst bf16 [C][R].
// ---------------------------------------------------------------------------
__global__ __launch_bounds__(256) void transpose_bf16(
    const float* __restrict__ src, u16* __restrict__ dst, int R, int C)
{
    __shared__ float T[64][65];
    const int t = threadIdx.x;
    const int r0 = blockIdx.x * 64, c0 = blockIdx.y * 64;
#pragma unroll
    for (int i = 0; i < 4; ++i) {
        int idx = i * 256 + t;
        int row = idx >> 4, col = (idx & 15) * 4;
        float4 v = *reinterpret_cast<const float4*>(&src[(size_t)(r0 + row) * C + c0 + col]);
        T[row][col] = v.x; T[row][col + 1] = v.y;
        T[row][col + 2] = v.z; T[row][col + 3] = v.w;
    }
    __syncthreads();
#pragma unroll
    for (int i = 0; i < 4; ++i) {
        int idx = i * 256 + t;
        int oc = idx >> 4, ok = (idx & 15) * 4;
        ushort4 o;
        o.x = bfu(T[ok][oc]);     o.y = bfu(T[ok + 1][oc]);
        o.z = bfu(T[ok + 2][oc]); o.w = bfu(T[ok + 3][oc]);
        *reinterpret_cast<ushort4*>(&dst[(size_t)(c0 + oc) * R + r0 + ok]) = o;
    }
}

// ---------------------------------------------------------------------------
// bf16 MFMA GEMM (m97 structure). fused=1: by -> proj/head; Q epilogue applies
// SM_SCALE. fused=0: by = n-tile, fp32 out.
// ---------------------------------------------------------------------------
__global__ __launch_bounds__(256) void gemm_mfma(
    const u16* __restrict__ A, const u16* __restrict__ Bt,
    float* __restrict__ Cf, u16* __restrict__ Cq, u16* __restrict__ Ck,
    u16* __restrict__ Cvt, int fused)
{
    __shared__ u16 As[128 * 64];
    __shared__ u16 Bs[64 * 64];

    const int tid  = threadIdx.x;
    const int lane = tid & 63;
    const int w    = tid >> 6;
    const int g    = lane >> 4;
    const int c15  = lane & 15;
    const int wr   = w >> 1, wc = w & 1;
    const int m0   = blockIdx.x * 128;
    const int by   = blockIdx.y;

    const u16* Bb = Bt + (size_t)by * (64 * 1024);
    const int srow8  = lane >> 3;
    const int schunk = lane & 7;

    f32x4 acc[4][2];
#pragma unroll
    for (int mf = 0; mf < 4; ++mf)
#pragma unroll
        for (int nf = 0; nf < 2; ++nf) acc[mf][nf] = f32x4{0.f, 0.f, 0.f, 0.f};

    for (int k0 = 0; k0 < GK; k0 += 64) {
#pragma unroll
        for (int c = 0; c < 4; ++c) {
            int row = c * 32 + w * 8 + srow8;
            int gc = schunk ^ (row & 7);
            gl_lds16(A + (size_t)(m0 + row) * GK + k0 + gc * 8,
                     As + c * 2048 + w * 512);
        }
#pragma unroll
        for (int c = 0; c < 2; ++c) {
            int row = c * 32 + w * 8 + srow8;
            int gc = schunk ^ (row & 7);
            gl_lds16(Bb + (size_t)row * GK + k0 + gc * 8,
                     Bs + c * 2048 + w * 512);
        }
        __syncthreads();

#pragma unroll
        for (int kc = 0; kc < 2; ++kc) {
            bf16x8 a[4], b[2];
#pragma unroll
            for (int mf = 0; mf < 4; ++mf) {
                int row = wr * 64 + mf * 16 + c15;
                int ch = (kc * 4 + g) ^ (row & 7);
                a[mf] = *reinterpret_cast<const bf16x8*>(As + row * 64 + ch * 8);
            }
#pragma unroll
            for (int nf = 0; nf < 2; ++nf) {
                int row = wc * 32 + nf * 16 + c15;
                int ch = (kc * 4 + g) ^ (row & 7);
                b[nf] = *reinterpret_cast<const bf16x8*>(Bs + row * 64 + ch * 8);
            }
#pragma unroll
            for (int mf = 0; mf < 4; ++mf)
#pragma unroll
                for (int nf = 0; nf < 2; ++nf)
                    acc[mf][nf] = __builtin_amdgcn_mfma_f32_16x16x32_bf16(
                        a[mf], b[nf], acc[mf][nf], 0, 0, 0);
        }
        __syncthreads();
    }

    // ---- epilogue ----
    if (!fused) {
#pragma unroll
        for (int mf = 0; mf < 4; ++mf) {
            int m = m0 + wr * 64 + mf * 16 + g * 4;
#pragma unroll
            for (int nf = 0; nf < 2; ++nf) {
                int n = by * 64 + wc * 32 + nf * 16 + c15;
#pragma unroll
                for (int r = 0; r < 4; ++r)
                    Cf[(size_t)(m + r) * 1024 + n] = acc[mf][nf][r];
            }
        }
        return;
    }
    const int proj = by >> 4;
    const int head = by & 15;
    const int b = m0 >> 11, l0 = m0 & 2047;
    if (proj < 2) {
        u16* C = proj ? Ck : Cq;
        const float qs = proj ? 1.f : SM_SCALE;   // pre-scale Q for softmax
        const size_t bh = ((size_t)(b * GH + head)) * GL * 64;
#pragma unroll
        for (int mf = 0; mf < 4; ++mf) {
            int l = l0 + wr * 64 + mf * 16 + g * 4;
#pragma unroll
            for (int nf = 0; nf < 2; ++nf) {
                int n = wc * 32 + nf * 16 + c15;
#pragma unroll
                for (int r = 0; r < 4; ++r)
                    C[bh + (size_t)(l + r) * 64 + n] = bfu(acc[mf][nf][r] * qs);
            }
        }
    } else {
        const size_t bh = ((size_t)(b * GH + head)) * 64 * GL;
#pragma unroll
        for (int mf = 0; mf < 4; ++mf) {
            int l = l0 + wr * 64 + mf * 16 + g * 4;
#pragma unroll
            for (int nf = 0; nf < 2; ++nf) {
                int n = wc * 32 + nf * 16 + c15;
                ushort4 o;
                o.x = bfu(acc[mf][nf][0]); o.y = bfu(acc[mf][nf][1]);
                o.z = bfu(acc[mf][nf][2]); o.w = bfu(acc[mf][nf][3]);
                *reinterpret_cast<ushort4*>(&Cvt[bh + (size_t)n * GL + l]) = o;
            }
        }
    }
}

// ---------------------------------------------------------------------------
// One 64-k KV step (32x32x16 MFMA, sigma-permuted K, in-register P).
// VARIANT ablation: 0=full, 1=no-PV, 2=no-softmax (others handled by caller).
// ---------------------------------------------------------------------------
template <bool DOMASK, int V>
__device__ __forceinline__ void attn_step32(
    const u16* __restrict__ Kt, const u16* __restrict__ Vt,
    const bf16x8* qf, int qrow, int j0, int qi, int hi,
    float& m_run, float& l_run, f32x16& o0, f32x16& o1)
{
    const int swz = qi & 7;

    f32x16 s0 = {0.f,0.f,0.f,0.f,0.f,0.f,0.f,0.f,0.f,0.f,0.f,0.f,0.f,0.f,0.f,0.f};
    f32x16 s1 = s0;
#pragma unroll
    for (int dc = 0; dc < 4; ++dc) {
        const int ch = ((dc * 2 + hi) ^ swz) * 8;
        bf16x8 kf0 = *reinterpret_cast<const bf16x8*>(Kt + qi * 64 + ch);
        bf16x8 kf1 = *reinterpret_cast<const bf16x8*>(Kt + (32 + qi) * 64 + ch);
        s0 = __builtin_amdgcn_mfma_f32_32x32x16_bf16(kf0, qf[dc], s0, 0, 0, 0);
        s1 = __builtin_amdgcn_mfma_f32_32x32x16_bf16(kf1, qf[dc], s1, 0, 0, 0);
    }

    if (DOMASK) {
#pragma unroll
        for (int r = 0; r < 16; ++r) {
            const int kl = (r & 3) + (((r >> 2) & 1) << 2) + (hi << 3)
                         + (((r >> 3) & 1) << 4);
            if (j0 + kl > qrow)      s0[r] = -__builtin_inff();
            if (j0 + 32 + kl > qrow) s1[r] = -__builtin_inff();
        }
    }

    unsigned pk0[8], pk1[8];
    if (V == 2) {
        // no-softmax: pack raw scores directly (garbage numerics, dummy out)
#pragma unroll
        for (int p = 0; p < 8; ++p) {
            pk0[p] = pack_trunc(s0[2 * p], s0[2 * p + 1]);
            pk1[p] = pack_trunc(s1[2 * p], s1[2 * p + 1]);
        }
        l_run += 1.0f;
    } else {
        float ma = fmaxf(s0[0], s0[1]), mb = fmaxf(s0[2], s0[3]);
        float mc = fmaxf(s1[0], s1[1]), md = fmaxf(s1[2], s1[3]);
#pragma unroll
        for (int r = 4; r < 16; r += 4) {
            ma = fmaxf(ma, fmaxf(s0[r], s0[r + 1]));
            mb = fmaxf(mb, fmaxf(s0[r + 2], s0[r + 3]));
            mc = fmaxf(mc, fmaxf(s1[r], s1[r + 1]));
            md = fmaxf(md, fmaxf(s1[r + 2], s1[r + 3]));
        }
        float mx = fmaxf(fmaxf(ma, mb), fmaxf(mc, md));
        mx = fmaxf(mx, __shfl_xor(mx, 32));

        if (!__all(mx <= m_run + RESCALE_THR)) {
            const float mnew = fmaxf(m_run, mx);
            const float scl  = fexp2(m_run - mnew);
            l_run *= scl;
            o0 *= scl;
            o1 *= scl;
            m_run = mnew;
        }

        float rsum = 0.f;
#pragma unroll
        for (int p = 0; p < 8; ++p) {
            float a = fexp2(s0[2 * p] - m_run), b = fexp2(s0[2 * p + 1] - m_run);
            float c = fexp2(s1[2 * p] - m_run), d = fexp2(s1[2 * p + 1] - m_run);
            rsum += (a + b) + (c + d);
            pk0[p] = pack_trunc(a, b);
            pk1[p] = pack_trunc(c, d);
        }
        rsum += __shfl_xor(rsum, 32);
        l_run += rsum;
    }

    if (V == 1) {
        // no-PV: keep P live without consuming it (rule #17: prevent DCE)
#pragma unroll
        for (int p = 0; p < 8; ++p)
            asm volatile("" :: "v"(pk0[p]), "v"(pk1[p]));
        return;
    }

    __builtin_amdgcn_s_setprio(1);
#pragma unroll
    for (int j2 = 0; j2 < 4; ++j2) {
        const int J4 = (j2 & 1) * 4;
        uint4 uu;
        if (j2 < 2) { uu.x = pk0[J4]; uu.y = pk0[J4 + 1]; uu.z = pk0[J4 + 2]; uu.w = pk0[J4 + 3]; }
        else        { uu.x = pk1[J4]; uu.y = pk1[J4 + 1]; uu.z = pk1[J4 + 2]; uu.w = pk1[J4 + 3]; }
        bf16x8 pf = __builtin_bit_cast(bf16x8, uu);
        const int chv = ((j2 * 2 + hi) ^ swz) * 8;
        bf16x8 vf0 = *reinterpret_cast<const bf16x8*>(Vt + qi * 64 + chv);
        bf16x8 vf1 = *reinterpret_cast<const bf16x8*>(Vt + (32 + qi) * 64 + chv);
        o0 = __builtin_amdgcn_mfma_f32_32x32x16_bf16(vf0, pf, o0, 0, 0, 0);
        o1 = __builtin_amdgcn_mfma_f32_32x32x16_bf16(vf1, pf, o1, 0, 0, 0);
    }
    __builtin_amdgcn_s_setprio(0);
}

// ---------------------------------------------------------------------------
// Causal flash attention, uniform-work decomposition (round-9 driver),
// template VARIANT ablation:
//   V=0 full (real output)   V=1 no-PV        V=2 no-softmax
//   V=3 staging+barriers only (skeleton)      V=4 no per-step staging
// V!=0 write only to the dummy buffer.
// ---------------------------------------------------------------------------
template <int V>
__global__ __launch_bounds__(256) void attn_mfma(
    const u16* __restrict__ qg, const u16* __restrict__ kg,
    const u16* __restrict__ vtg, u16* __restrict__ og)
{
    __shared__ u16 Ksh[2][2][4096];
    __shared__ u16 Vsh[2][2][4096];

    const int tid  = threadIdx.x;
    const int lane = tid & 63;
    const int w    = tid >> 6;
    const int wl   = w & 1;
    const int g    = w >> 1;
    const int qi   = lane & 31;
    const int hi   = lane >> 5;

    const int bid  = blockIdx.x;
    const int slot = bid & 7;
    const int idx  = bid >> 3;
    const int bh   = slot * 4 + (idx >> 4);
    const int rem  = idx & 15;
    const int p    = rem >> 1;
    const int h    = rem & 1;

    const size_t qkb  = (size_t)bh * GL * 64;
    const size_t vtbo = (size_t)bh * 64 * GL;

    float* scr = (float*)&Ksh[0][0][0];

    auto stage = [&](int t, int s) {
        u16* kd = &Ksh[g][s][0];
        u16* vd = &Vsh[g][s][0];
#pragma unroll
        for (int cc = 0; cc < 4; ++cc) {
            const int row = wl * 32 + cc * 8 + (lane >> 3);
            const int gc  = (lane & 7) ^ (row & 7);
            const int ksrc = t * 64 + (row & 32) + sig5(row & 31);
            gl_lds16(kg + qkb + (size_t)ksrc * 64 + gc * 8,
                     kd + wl * 2048 + cc * 512);
            gl_lds16(vtg + vtbo + (size_t)row * GL + t * 64 + gc * 8,
                     vd + wl * 2048 + cc * 512);
        }
    };

    const int b  = bh >> 4, hh = bh & 15;

#pragma unroll
    for (int cpick = 0; cpick < 2; ++cpick) {
        const int c = cpick ? (15 - p) : p;
        const int qrow = c * 128 + h * 64 + wl * 32 + qi;

        bf16x8 qf[4];
#pragma unroll
        for (int dc = 0; dc < 4; ++dc)
            qf[dc] = *reinterpret_cast<const bf16x8*>(
                qg + qkb + (size_t)qrow * 64 + dc * 16 + hi * 8);

        const int nA = c + 1;
        const int n  = (g == 0) ? nA : ((h == 0) ? c : c + 1);

        float m_run = -__builtin_inff(), l_run = 0.f;
        f32x16 o0 = {0.f,0.f,0.f,0.f,0.f,0.f,0.f,0.f,0.f,0.f,0.f,0.f,0.f,0.f,0.f,0.f};
        f32x16 o1 = o0;

        if (n > 0) stage(g, 0);
        __syncthreads();

        for (int i = 0; i < nA; ++i) {
            if (i < n) {
                if (V != 4) { if (i + 1 < n) stage(2 * (i + 1) + g, (i + 1) & 1); }
                if (V != 3) {
                    const int sl = (V == 4) ? 0 : (i & 1);
                    const u16* Kt = &Ksh[g][sl][0];
                    const u16* Vt = &Vsh[g][sl][0];
                    const int j0 = (2 * i + g) * 64;
                    if (i == c && g == h)
                        attn_step32<true, V>(Kt, Vt, qf, qrow, j0, qi, hi, m_run, l_run, o0, o1);
                    else
                        attn_step32<false, V>(Kt, Vt, qf, qrow, j0, qi, hi, m_run, l_run, o0, o1);
                }
            }
            __syncthreads();
        }

        // ---- combine partials across the parity groups (exact fp32) ----
        const int sidx = (wl * 64 + lane) * 34;
        if (g == 1) {
#pragma unroll
            for (int r = 0; r < 16; ++r) {
                scr[sidx + r]      = o0[r];
                scr[sidx + 16 + r] = o1[r];
            }
            scr[sidx + 32] = m_run;
            scr[sidx + 33] = l_run;
        }
        __syncthreads();
        if (g == 0) {
            const float mB = scr[sidx + 32], lB = scr[sidx + 33];
            const float m  = fmaxf(m_run, mB);
            const float sA = fexp2(m_run - m);
            const float sB = fexp2(mB - m);
            const float inv = 1.f / (l_run * sA + lB * sB);
            u16* obase = og + ((size_t)(b * GL + qrow)) * 1024 + hh * 64 + 4 * hi;
#pragma unroll
            for (int rq = 0; rq < 4; ++rq) {
                ushort4 w0, w1;
                w0.x = bfu((o0[4*rq]   * sA + scr[sidx + 4*rq]   * sB) * inv);
                w0.y = bfu((o0[4*rq+1] * sA + scr[sidx + 4*rq+1] * sB) * inv);
                w0.z = bfu((o0[4*rq+2] * sA + scr[sidx + 4*rq+2] * sB) * inv);
                w0.w = bfu((o0[4*rq+3] * sA + scr[sidx + 4*rq+3] * sB) * inv);
                *reinterpret_cast<ushort4*>(obase + 8 * rq) = w0;
                w1.x = bfu((o1[4*rq]   * sA + scr[sidx + 16 + 4*rq]   * sB) * inv);
                w1.y = bfu((o1[4*rq+1] * sA + scr[sidx + 16 + 4*rq+1] * sB) * inv);
                w1.z = bfu((o1[4*rq+2] * sA + scr[sidx + 16 + 4*rq+2] * sB) * inv);
                w1.w = bfu((o1[4*rq+3] * sA + scr[sidx + 16 + 4*rq+3] * sB) * inv);
                *reinterpret_cast<ushort4*>(obase + 32 + 8 * rq) = w1;
            }
        }
        __syncthreads();
    }

    if (V == 3) {
        // consume the staged LDS so staging can't be elided (dummy write)
        og[(size_t)bid * 256 + tid] =
            Ksh[0][0][tid] ^ Vsh[0][0][tid] ^ Ksh[1][1][tid] ^ Vsh[1][1][tid];
    }
}

// ---------------------------------------------------------------------------
extern "C" void kernel_launch(void* const* d_in, const int* in_sizes, int n_in,
                              void* d_out, int out_size, void* d_ws, size_t ws_size,
                              hipStream_t stream) {
    const float* emb = (const float*)d_in[0];
    const float* Wq  = (const float*)d_in[1];
    const float* Wk  = (const float*)d_in[2];
    const float* Wv  = (const float*)d_in[3];
    const float* Wo  = (const float*)d_in[4];
    float* out = (float*)d_out;

    char* ws = (char*)d_ws;
    u16* qb   = (u16*)(ws);
    u16* kb   = (u16*)(ws + ( 8u << 20));
    u16* vtb  = (u16*)(ws + (16u << 20));
    u16* ab   = (u16*)(ws + (24u << 20));
    u16* embb = (u16*)(ws + (32u << 20));   // rewritten by cast_bf16 every call
    u16* wqt  = (u16*)(ws + (40u << 20));
    u16* wot  = (u16*)(ws + (46u << 20));

    dim3 blk(256);

    cast_bf16<<<dim3(2048), blk, 0, stream>>>(emb, embb, GM * GK / 8);
    transpose_qkv<<<dim3(16, 1, 48), blk, 0, stream>>>(Wq, Wk, Wv, wqt);
    transpose_bf16<<<dim3(16, 16, 1), blk, 0, stream>>>(Wo, wot, 1024, 1024);

    // fused Q/K/V projections (one dispatch, 48 n-slices)
    gemm_mfma<<<dim3(GM / 128, 48), blk, 0, stream>>>(
        embb, wqt, nullptr, qb, kb, vtb, 1);

    // ---- ABLATION: variants write to embb (dummy, regenerated each call) ----
    attn_mfma<3><<<dim3(512), blk, 0, stream>>>(qb, kb, vtb, embb);  // skeleton
    attn_mfma<4><<<dim3(512), blk, 0, stream>>>(qb, kb, vtb, embb);  // no staging
    attn_mfma<1><<<dim3(512), blk, 0, stream>>>(qb, kb, vtb, embb);  // no PV
    attn_mfma<2><<<dim3(512), blk, 0, stream>>>(qb, kb, vtb, embb);  // no softmax

    // real attention
    attn_mfma<0><<<dim3(512), blk, 0, stream>>>(qb, kb, vtb, ab);

    // output projection
    gemm_mfma<<<dim3(GM / 128, 16), blk, 0, stream>>>(
        ab, wot, out, nullptr, nullptr, nullptr, 0);
}

// Round 11
// 127.182 us; speedup vs baseline: 1.6580x; 1.6580x over previous
//
#include <hip/hip_runtime.h>
#include <hip/hip_bf16.h>

// B=2, L=2048, D=1024, H=16, HD=64.  M = B*L = 4096, K = D = 1024.
// ws (bytes):
//   qb   @ 0MB   bf16 [32][2048][64]   (Q pre-scaled by SM_SCALE)
//   kb   @ 8MB   bf16 [32][2048][64]
//   vtb  @16MB   bf16 [32][64][2048]   (V transposed)
//   ab   @24MB   bf16 [4096][1024]     (attn concat out)
//   embb @32MB   bf16 [4096][1024]
//   wqt  @40MB   bf16 [48][64][1024]   (wqt/wkt/wvt contiguous, 2MB each)
//   wot  @46MB   bf16 [1024][1024]     (Wo transposed)

#define GM 4096
#define GK 1024
#define GL 2048
#define GH 16

typedef __attribute__((ext_vector_type(8))) short bf16x8;
typedef __attribute__((ext_vector_type(4))) float f32x4;
typedef __attribute__((ext_vector_type(16))) float f32x16;
typedef unsigned short u16;

__device__ __forceinline__ u16 bfu(float x) {
    __hip_bfloat16 h = __float2bfloat16(x);
    return *reinterpret_cast<u16*>(&h);
}
__device__ __forceinline__ unsigned pack_bf16(float a, float b) {
    return ((unsigned)bfu(b) << 16) | bfu(a);
}
// truncation-pack two f32 -> {bf16(a) lo, bf16(b) hi} in one v_perm_b32
__device__ __forceinline__ unsigned pack_trunc(float a, float b) {
    return __builtin_amdgcn_perm(__float_as_uint(b), __float_as_uint(a), 0x07060302u);
}
__device__ __forceinline__ void gl_lds16(const void* g, void* l) {
    __builtin_amdgcn_global_load_lds(
        (__attribute__((address_space(1))) void*)(g),
        (__attribute__((address_space(3))) void*)(l),
        16, 0, 0);
}
__device__ __forceinline__ float fexp2(float x) {
#if __has_builtin(__builtin_amdgcn_exp2f)
    return __builtin_amdgcn_exp2f(x);
#else
    return __expf(x * 0.6931471805599453f);
#endif
}
// sigma: staged K-row p holds true kv sig5(p) (swap bits 2<->3, keep 0,1,4).
// Makes QK^T C-regs land exactly in PV B-fragment order (P in registers).
__device__ __forceinline__ int sig5(int c) {
    return (c & 3) | (((c >> 3) & 1) << 2) | (((c >> 2) & 1) << 3) | (c & 16);
}
// LDS swizzles (both-sides): K 8-granule rows, V 4-granule rows.
__device__ __forceinline__ int kswz(int row) { return (row & 7) ^ (row >> 3); }
__device__ __forceinline__ int vswz(int row) { return ((row & 3) ^ ((row >> 3) & 3)); }

// wave-local counted waits (T4, per-wave): 8 = one in-flight stage batch.
#define WAITV8() do { asm volatile("s_waitcnt vmcnt(8)" ::: "memory"); \
                      __builtin_amdgcn_sched_barrier(0); } while (0)
#define WAITV0() do { asm volatile("s_waitcnt vmcnt(0)" ::: "memory"); \
                      __builtin_amdgcn_sched_barrier(0); } while (0)

// 0.125 (1/sqrt(64)) folded with log2(e): softmax done in exp2 domain.
#define SM_SCALE 0.1803368801111204f
#define RESCALE_THR 8.0f

// ---------------------------------------------------------------------------
// fp32 -> bf16 cast, 8 elements/thread.
// ---------------------------------------------------------------------------
__global__ __launch_bounds__(256) void cast_bf16(
    const float* __restrict__ src, u16* __restrict__ dst, int n8)
{
    int i = blockIdx.x * 256 + threadIdx.x;
    if (i >= n8) return;
    float4 v0 = reinterpret_cast<const float4*>(src)[i * 2];
    float4 v1 = reinterpret_cast<const float4*>(src)[i * 2 + 1];
    uint4 o;
    o.x = pack_bf16(v0.x, v0.y);
    o.y = pack_bf16(v0.z, v0.w);
    o.z = pack_bf16(v1.x, v1.y);
    o.w = pack_bf16(v1.z, v1.w);
    reinterpret_cast<uint4*>(dst)[i] = o;
}

// ---------------------------------------------------------------------------
// Fused Wq/Wk/Wv transpose+convert: z in [0,48) -> head (z&15) of proj (z>>4).
// ---------------------------------------------------------------------------
__global__ __launch_bounds__(256) void transpose_qkv(
    const float* __restrict__ Wq, const float* __restrict__ Wk,
    const float* __restrict__ Wv, u16* __restrict__ dst)
{
    __shared__ float T[64][65];
    const int t = threadIdx.x;
    const int z = blockIdx.z;
    const int r0 = blockIdx.x * 64;
    const float* s = (z < 16 ? Wq : (z < 32 ? Wk : Wv)) + (size_t)(z & 15) * 65536;
    u16* d = dst + (size_t)z * 65536;
#pragma unroll
    for (int i = 0; i < 4; ++i) {
        int idx = i * 256 + t;
        int row = idx >> 4, col = (idx & 15) * 4;
        float4 v = *reinterpret_cast<const float4*>(&s[(size_t)(r0 + row) * 64 + col]);
        T[row][col] = v.x; T[row][col + 1] = v.y;
        T[row][col + 2] = v.z; T[row][col + 3] = v.w;
    }
    __syncthreads();
#pragma unroll
    for (int i = 0; i < 4; ++i) {
        int idx = i * 256 + t;
        int oc = idx >> 4, ok = (idx & 15) * 4;
        ushort4 o;
        o.x = bfu(T[ok][oc]);     o.y = bfu(T[ok + 1][oc]);
        o.z = bfu(T[ok + 2][oc]); o.w = bfu(T[ok + 3][oc]);
        *reinterpret_cast<ushort4*>(&d[(size_t)oc * 1024 + r0 + ok]) = o;
    }
}

// ---------------------------------------------------------------------------
// Generic transpose+convert (for Wo): src fp32 [R][C] -> dst bf16 [C][R].
// ---------------------------------------------------------------------------
__global__ __launch_bounds__(256) void transpose_bf16(
    const float* __restrict__ src, u16* __restrict__ dst, int R, int C)
{
    __shared__ float T[64][65];
    const int t = threadIdx.x;
    const int r0 = blockIdx.x * 64, c0 = blockIdx.y * 64;
#pragma unroll
    for (int i = 0; i < 4; ++i) {
        int idx = i * 256 + t;
        int row = idx >> 4, col = (idx & 15) * 4;
        float4 v = *reinterpret_cast<const float4*>(&src[(size_t)(r0 + row) * C + c0 + col]);
        T[row][col] = v.x; T[row][col + 1] = v.y;
        T[row][col + 2] = v.z; T[row][col + 3] = v.w;
    }
    __syncthreads();
#pragma unroll
    for (int i = 0; i < 4; ++i) {
        int idx = i * 256 + t;
        int oc = idx >> 4, ok = (idx & 15) * 4;
        ushort4 o;
        o.x = bfu(T[ok][oc]);     o.y = bfu(T[ok + 1][oc]);
        o.z = bfu(T[ok + 2][oc]); o.w = bfu(T[ok + 3][oc]);
        *reinterpret_cast<ushort4*>(&dst[(size_t)(c0 + oc) * R + r0 + ok]) = o;
    }
}

// ---------------------------------------------------------------------------
// bf16 MFMA GEMM (m97 structure, unchanged). fused=1: by -> proj/head;
// Q epilogue applies SM_SCALE. fused=0: by = n-tile, fp32 out.
// ---------------------------------------------------------------------------
__global__ __launch_bounds__(256) void gemm_mfma(
    const u16* __restrict__ A, const u16* __restrict__ Bt,
    float* __restrict__ Cf, u16* __restrict__ Cq, u16* __restrict__ Ck,
    u16* __restrict__ Cvt, int fused)
{
    __shared__ u16 As[128 * 64];
    __shared__ u16 Bs[64 * 64];

    const int tid  = threadIdx.x;
    const int lane = tid & 63;
    const int w    = tid >> 6;
    const int g    = lane >> 4;
    const int c15  = lane & 15;
    const int wr   = w >> 1, wc = w & 1;
    const int m0   = blockIdx.x * 128;
    const int by   = blockIdx.y;

    const u16* Bb = Bt + (size_t)by * (64 * 1024);
    const int srow8  = lane >> 3;
    const int schunk = lane & 7;

    f32x4 acc[4][2];
#pragma unroll
    for (int mf = 0; mf < 4; ++mf)
#pragma unroll
        for (int nf = 0; nf < 2; ++nf) acc[mf][nf] = f32x4{0.f, 0.f, 0.f, 0.f};

    for (int k0 = 0; k0 < GK; k0 += 64) {
#pragma unroll
        for (int c = 0; c < 4; ++c) {
            int row = c * 32 + w * 8 + srow8;
            int gc = schunk ^ (row & 7);
            gl_lds16(A + (size_t)(m0 + row) * GK + k0 + gc * 8,
                     As + c * 2048 + w * 512);
        }
#pragma unroll
        for (int c = 0; c < 2; ++c) {
            int row = c * 32 + w * 8 + srow8;
            int gc = schunk ^ (row & 7);
            gl_lds16(Bb + (size_t)row * GK + k0 + gc * 8,
                     Bs + c * 2048 + w * 512);
        }
        __syncthreads();

#pragma unroll
        for (int kc = 0; kc < 2; ++kc) {
            bf16x8 a[4], b[2];
#pragma unroll
            for (int mf = 0; mf < 4; ++mf) {
                int row = wr * 64 + mf * 16 + c15;
                int ch = (kc * 4 + g) ^ (row & 7);
                a[mf] = *reinterpret_cast<const bf16x8*>(As + row * 64 + ch * 8);
            }
#pragma unroll
            for (int nf = 0; nf < 2; ++nf) {
                int row = wc * 32 + nf * 16 + c15;
                int ch = (kc * 4 + g) ^ (row & 7);
                b[nf] = *reinterpret_cast<const bf16x8*>(Bs + row * 64 + ch * 8);
            }
#pragma unroll
            for (int mf = 0; mf < 4; ++mf)
#pragma unroll
                for (int nf = 0; nf < 2; ++nf)
                    acc[mf][nf] = __builtin_amdgcn_mfma_f32_16x16x32_bf16(
                        a[mf], b[nf], acc[mf][nf], 0, 0, 0);
        }
        __syncthreads();
    }

    if (!fused) {
#pragma unroll
        for (int mf = 0; mf < 4; ++mf) {
            int m = m0 + wr * 64 + mf * 16 + g * 4;
#pragma unroll
            for (int nf = 0; nf < 2; ++nf) {
                int n = by * 64 + wc * 32 + nf * 16 + c15;
#pragma unroll
                for (int r = 0; r < 4; ++r)
                    Cf[(size_t)(m + r) * 1024 + n] = acc[mf][nf][r];
            }
        }
        return;
    }
    const int proj = by >> 4;
    const int head = by & 15;
    const int b = m0 >> 11, l0 = m0 & 2047;
    if (proj < 2) {
        u16* C = proj ? Ck : Cq;
        const float qs = proj ? 1.f : SM_SCALE;
        const size_t bh = ((size_t)(b * GH + head)) * GL * 64;
#pragma unroll
        for (int mf = 0; mf < 4; ++mf) {
            int l = l0 + wr * 64 + mf * 16 + g * 4;
#pragma unroll
            for (int nf = 0; nf < 2; ++nf) {
                int n = wc * 32 + nf * 16 + c15;
#pragma unroll
                for (int r = 0; r < 4; ++r)
                    C[bh + (size_t)(l + r) * 64 + n] = bfu(acc[mf][nf][r] * qs);
            }
        }
    } else {
        const size_t bh = ((size_t)(b * GH + head)) * 64 * GL;
#pragma unroll
        for (int mf = 0; mf < 4; ++mf) {
            int l = l0 + wr * 64 + mf * 16 + g * 4;
#pragma unroll
            for (int nf = 0; nf < 2; ++nf) {
                int n = wc * 32 + nf * 16 + c15;
                ushort4 o;
                o.x = bfu(acc[mf][nf][0]); o.y = bfu(acc[mf][nf][1]);
                o.z = bfu(acc[mf][nf][2]); o.w = bfu(acc[mf][nf][3]);
                *reinterpret_cast<ushort4*>(&Cvt[bh + (size_t)n * GL + l]) = o;
            }
        }
    }
}

// ---------------------------------------------------------------------------
// One 32-kv step: one 32x32 S tile (4 MFMA), in-register P (sigma staging),
// PV 4 MFMA. DM = diagonal tile (mask kv > qi, tile-relative).
// ---------------------------------------------------------------------------
template <bool DM>
__device__ __forceinline__ void step32(
    const u16* __restrict__ Kt, const u16* __restrict__ Vt,
    const bf16x8* qf, int qi, int hi,
    float& m_run, float& l_run, f32x16& o0, f32x16& o1)
{
    const int ks = kswz(qi);

    // ---- S^T = K . Q^T (K from sigma-permuted, swizzled LDS) ----
    f32x16 s = {0.f,0.f,0.f,0.f,0.f,0.f,0.f,0.f,0.f,0.f,0.f,0.f,0.f,0.f,0.f,0.f};
#pragma unroll
    for (int dc = 0; dc < 4; ++dc) {
        const int ch = (dc * 2 + hi) ^ ks;
        bf16x8 kf = *reinterpret_cast<const bf16x8*>(Kt + qi * 64 + ch * 8);
        s = __builtin_amdgcn_mfma_f32_32x32x16_bf16(kf, qf[dc], s, 0, 0, 0);
    }

    // reg r holds kv (tile-relative) = 16*(r>>3) + 8*hi + (r&7)
    if (DM) {
#pragma unroll
        for (int r = 0; r < 16; ++r) {
            const int kl = 16 * (r >> 3) + 8 * hi + (r & 7);
            if (kl > qi) s[r] = -__builtin_inff();
        }
    }

    // ---- row max (15 fmax) + single cross-lane xor-32 ----
    float m01 = fmaxf(s[0], s[1]),   m23 = fmaxf(s[2], s[3]);
    float m45 = fmaxf(s[4], s[5]),   m67 = fmaxf(s[6], s[7]);
    float m89 = fmaxf(s[8], s[9]),   mab = fmaxf(s[10], s[11]);
    float mcd = fmaxf(s[12], s[13]), mef = fmaxf(s[14], s[15]);
    float mx = fmaxf(fmaxf(fmaxf(m01, m23), fmaxf(m45, m67)),
                     fmaxf(fmaxf(m89, mab), fmaxf(mcd, mef)));
    mx = fmaxf(mx, __shfl_xor(mx, 32));

    // ---- defer-max rescale (T13) ----
    if (!__all(mx <= m_run + RESCALE_THR)) {
        const float mnew = fmaxf(m_run, mx);
        const float scl  = fexp2(m_run - mnew);   // first tile: exp2(-inf)=0
        l_run *= scl;
        o0 *= scl;
        o1 *= scl;
        m_run = mnew;
    }

    // ---- exp + pack: pk[j] = {p[2j], p[2j+1]}; frag m = pk[4m..4m+3] ----
    float rsum = 0.f;
    unsigned pk[8];
#pragma unroll
    for (int j = 0; j < 8; ++j) {
        float a = fexp2(s[2 * j]     - m_run);
        float b = fexp2(s[2 * j + 1] - m_run);
        rsum += a + b;
        pk[j] = pack_trunc(a, b);
    }
    rsum += __shfl_xor(rsum, 32);
    l_run += rsum;

    // ---- O^T += V^T . P^T (P in registers) ----
    __builtin_amdgcn_s_setprio(1);
#pragma unroll
    for (int m = 0; m < 2; ++m) {
        uint4 uu;
        uu.x = pk[4 * m]; uu.y = pk[4 * m + 1];
        uu.z = pk[4 * m + 2]; uu.w = pk[4 * m + 3];
        bf16x8 pf = __builtin_bit_cast(bf16x8, uu);
        const int x = m * 2 + hi;
        bf16x8 vf0 = *reinterpret_cast<const bf16x8*>(
            Vt + qi * 32 + ((x ^ vswz(qi)) * 8));
        bf16x8 vf1 = *reinterpret_cast<const bf16x8*>(
            Vt + (32 + qi) * 32 + ((x ^ vswz(32 + qi)) * 8));
        o0 = __builtin_amdgcn_mfma_f32_32x32x16_bf16(vf0, pf, o0, 0, 0, 0);
        o1 = __builtin_amdgcn_mfma_f32_32x32x16_bf16(vf1, pf, o1, 0, 0, 0);
    }
    __builtin_amdgcn_s_setprio(0);
}

// ---------------------------------------------------------------------------
// Barrier-free causal flash attention. 1024 blocks x 128 threads (2 waves).
// Each WAVE owns one 32-row q-chunk: private K/V LDS double-buffer staged by
// the wave via global_load_lds, wave-local counted s_waitcnt vmcnt(8) (no
// __syncthreads anywhere). Decode: hg=bid&7 (XCD; heads hg*4..+3 pinned),
// C = 63-((bid>>3)&63) (longest chunks dispatch first), hpair=bid>>9.
// Wave w -> head hg*4 + hpair*2 + w, chunk C (KV tiles 0..C of 32 rows).
// LDS 32KB/block -> 4 blocks/CU = 8 waves/CU.
// ---------------------------------------------------------------------------
__global__ __launch_bounds__(128) void attn_mfma(
    const u16* __restrict__ qg, const u16* __restrict__ kg,
    const u16* __restrict__ vtg, u16* __restrict__ og)
{
    __shared__ u16 Ksh[2][2][2048];   // [wave][buf][32 rows x 64]
    __shared__ u16 Vsh[2][2][2048];   // [wave][buf][64 rows x 32]

    const int tid  = threadIdx.x;
    const int lane = tid & 63;
    const int w    = tid >> 6;
    const int qi   = lane & 31;
    const int hi   = lane >> 5;

    const int bid = blockIdx.x;
    const int hg  = bid & 7;
    const int C   = 63 - ((bid >> 3) & 63);
    const int hp  = bid >> 9;
    const int bh  = hg * 4 + hp * 2 + w;

    const size_t qkb  = (size_t)bh * GL * 64;
    const size_t vtbo = (size_t)bh * 64 * GL;

    const int qrow = C * 32 + qi;
    bf16x8 qf[4];
#pragma unroll
    for (int dc = 0; dc < 4; ++dc)
        qf[dc] = *reinterpret_cast<const bf16x8*>(
            qg + qkb + (size_t)qrow * 64 + dc * 16 + hi * 8);

    u16* K0 = &Ksh[w][0][0];  u16* K1 = &Ksh[w][1][0];
    u16* V0 = &Vsh[w][0][0];  u16* V1 = &Vsh[w][1][0];

    // wave-private staging: K tile 32x64 (sigma rows, swizzled src), V 64x32.
    auto stage = [&](int t, u16* kd, u16* vd) {
#pragma unroll
        for (int i = 0; i < 4; ++i) {
            const int rho = i * 8 + (lane >> 3);          // staged K row 0..31
            const int gck = (lane & 7) ^ kswz(rho);
            gl_lds16(kg + qkb + (size_t)(t * 32 + sig5(rho)) * 64 + gck * 8,
                     kd + i * 512);
            const int rv  = i * 16 + (lane >> 2);         // staged V row 0..63
            const int gcv = (lane & 3) ^ vswz(rv);
            gl_lds16(vtg + vtbo + (size_t)rv * GL + t * 32 + gcv * 8,
                     vd + i * 512);
        }
    };

    float m_run = -__builtin_inff(), l_run = 0.f;
    f32x16 o0 = {0.f,0.f,0.f,0.f,0.f,0.f,0.f,0.f,0.f,0.f,0.f,0.f,0.f,0.f,0.f,0.f};
    f32x16 o1 = o0;

    stage(0, K0, V0);
    int t = 0;
    while (t + 2 <= C) {
        stage(t + 1, K1, V1);
        WAITV8();                       // buf0 (tile t) landed; t+1 in flight
        step32<false>(K0, V0, qf, qi, hi, m_run, l_run, o0, o1);
        stage(t + 2, K0, V0);
        WAITV8();                       // buf1 (tile t+1) landed; t+2 in flight
        step32<false>(K1, V1, qf, qi, hi, m_run, l_run, o0, o1);
        t += 2;
    }
    if (t < C) {                        // t == C-1: tile t in buf0, diag in buf1
        stage(C, K1, V1);
        WAITV8();
        step32<false>(K0, V0, qf, qi, hi, m_run, l_run, o0, o1);
        WAITV0();
        step32<true>(K1, V1, qf, qi, hi, m_run, l_run, o0, o1);
    } else {                            // t == C: diag already in buf0
        WAITV0();
        step32<true>(K0, V0, qf, qi, hi, m_run, l_run, o0, o1);
    }

    // ---- epilogue: O[qrow][hd], hd = 4*hi + (r&3) + 8*(r>>2) (+32 for o1) ----
    const int b = bh >> 4, h = bh & 15;
    const float inv = 1.f / l_run;
    u16* obase = og + ((size_t)(b * GL + qrow)) * 1024 + h * 64 + 4 * hi;
#pragma unroll
    for (int rq = 0; rq < 4; ++rq) {
        ushort4 w0, w1;
        w0.x = bfu(o0[4 * rq] * inv);     w0.y = bfu(o0[4 * rq + 1] * inv);
        w0.z = bfu(o0[4 * rq + 2] * inv); w0.w = bfu(o0[4 * rq + 3] * inv);
        *reinterpret_cast<ushort4*>(obase + 8 * rq) = w0;
        w1.x = bfu(o1[4 * rq] * inv);     w1.y = bfu(o1[4 * rq + 1] * inv);
        w1.z = bfu(o1[4 * rq + 2] * inv); w1.w = bfu(o1[4 * rq + 3] * inv);
        *reinterpret_cast<ushort4*>(obase + 32 + 8 * rq) = w1;
    }
}

// ---------------------------------------------------------------------------
extern "C" void kernel_launch(void* const* d_in, const int* in_sizes, int n_in,
                              void* d_out, int out_size, void* d_ws, size_t ws_size,
                              hipStream_t stream) {
    const float* emb = (const float*)d_in[0];
    const float* Wq  = (const float*)d_in[1];
    const float* Wk  = (const float*)d_in[2];
    const float* Wv  = (const float*)d_in[3];
    const float* Wo  = (const float*)d_in[4];
    float* out = (float*)d_out;

    char* ws = (char*)d_ws;
    u16* qb   = (u16*)(ws);
    u16* kb   = (u16*)(ws + ( 8u << 20));
    u16* vtb  = (u16*)(ws + (16u << 20));
    u16* ab   = (u16*)(ws + (24u << 20));
    u16* embb = (u16*)(ws + (32u << 20));
    u16* wqt  = (u16*)(ws + (40u << 20));
    u16* wot  = (u16*)(ws + (46u << 20));

    dim3 blk(256);

    cast_bf16<<<dim3(2048), blk, 0, stream>>>(emb, embb, GM * GK / 8);
    transpose_qkv<<<dim3(16, 1, 48), blk, 0, stream>>>(Wq, Wk, Wv, wqt);
    transpose_bf16<<<dim3(16, 16, 1), blk, 0, stream>>>(Wo, wot, 1024, 1024);

    // fused Q/K/V projections (one dispatch, 48 n-slices)
    gemm_mfma<<<dim3(GM / 128, 48), blk, 0, stream>>>(
        embb, wqt, nullptr, qb, kb, vtb, 1);

    // attention: barrier-free, wave-private pipelines
    attn_mfma<<<dim3(1024), dim3(128), 0, stream>>>(qb, kb, vtb, ab);

    // output projection
    gemm_mfma<<<dim3(GM / 128, 16), blk, 0, stream>>>(
        ab, wot, out, nullptr, nullptr, nullptr, 0);
}

// Round 12
// 115.288 us; speedup vs baseline: 1.8290x; 1.1032x over previous
//
#include <hip/hip_runtime.h>
#include <hip/hip_bf16.h>

// B=2, L=2048, D=1024, H=16, HD=64.  M = B*L = 4096, K = D = 1024.
// ws (bytes):
//   qb   @ 0MB   bf16 [32][2048][64]   (Q pre-scaled by SM_SCALE)
//   kb   @ 8MB   bf16 [32][2048][64]
//   vtb  @16MB   bf16 [32][64][2048]   (V transposed)
//   ab   @24MB   bf16 [4096][1024]     (attn concat out)
//   embb @32MB   bf16 [4096][1024]
//   wqt  @40MB   bf16 [48][64][1024]   (wqt/wkt/wvt contiguous, 2MB each)
//   wot  @46MB   bf16 [1024][1024]     (Wo transposed)

#define GM 4096
#define GK 1024
#define GL 2048
#define GH 16

typedef __attribute__((ext_vector_type(8))) short bf16x8;
typedef __attribute__((ext_vector_type(4))) float f32x4;
typedef __attribute__((ext_vector_type(16))) float f32x16;
typedef unsigned short u16;

__device__ __forceinline__ u16 bfu(float x) {
    __hip_bfloat16 h = __float2bfloat16(x);
    return *reinterpret_cast<u16*>(&h);
}
__device__ __forceinline__ unsigned pack_bf16(float a, float b) {
    return ((unsigned)bfu(b) << 16) | bfu(a);
}
// truncation-pack two f32 -> {bf16(a) lo, bf16(b) hi} in one v_perm_b32
__device__ __forceinline__ unsigned pack_trunc(float a, float b) {
    return __builtin_amdgcn_perm(__float_as_uint(b), __float_as_uint(a), 0x07060302u);
}
__device__ __forceinline__ void gl_lds16(const void* g, void* l) {
    __builtin_amdgcn_global_load_lds(
        (__attribute__((address_space(1))) void*)(g),
        (__attribute__((address_space(3))) void*)(l),
        16, 0, 0);
}
__device__ __forceinline__ float fexp2(float x) {
#if __has_builtin(__builtin_amdgcn_exp2f)
    return __builtin_amdgcn_exp2f(x);
#else
    return __expf(x * 0.6931471805599453f);
#endif
}
// sigma: staged K-row p holds true kv sig5(p) within each 32-half.
// Makes QK^T C-regs land exactly in PV B-fragment order (P in registers).
__device__ __forceinline__ int sig5(int c) {
    return (c & 3) | (((c >> 3) & 1) << 2) | (((c >> 2) & 1) << 3) | (c & 16);
}
// full-row XOR swizzle (round-11: measured 0 bank conflicts)
__device__ __forceinline__ int rswz(int row) {
    return (row & 7) ^ ((row >> 3) & 7);
}

// counted waits (T4): 4 = one in-flight stage batch per wave.
#define WAITV4() do { asm volatile("s_waitcnt vmcnt(4)" ::: "memory"); \
                      __builtin_amdgcn_sched_barrier(0); } while (0)
#define WAITV0() do { asm volatile("s_waitcnt vmcnt(0)" ::: "memory"); \
                      __builtin_amdgcn_sched_barrier(0); } while (0)
// raw barrier (no vmcnt drain) fenced against reordering
#define BARRIER() do { __builtin_amdgcn_sched_barrier(0); \
                       __builtin_amdgcn_s_barrier(); \
                       __builtin_amdgcn_sched_barrier(0); } while (0)

// 0.125 (1/sqrt(64)) folded with log2(e): softmax done in exp2 domain.
#define SM_SCALE 0.1803368801111204f
#define RESCALE_THR 8.0f

// ---------------------------------------------------------------------------
// fp32 -> bf16 cast, 8 elements/thread.
// ---------------------------------------------------------------------------
__global__ __launch_bounds__(256) void cast_bf16(
    const float* __restrict__ src, u16* __restrict__ dst, int n8)
{
    int i = blockIdx.x * 256 + threadIdx.x;
    if (i >= n8) return;
    float4 v0 = reinterpret_cast<const float4*>(src)[i * 2];
    float4 v1 = reinterpret_cast<const float4*>(src)[i * 2 + 1];
    uint4 o;
    o.x = pack_bf16(v0.x, v0.y);
    o.y = pack_bf16(v0.z, v0.w);
    o.z = pack_bf16(v1.x, v1.y);
    o.w = pack_bf16(v1.z, v1.w);
    reinterpret_cast<uint4*>(dst)[i] = o;
}

// ---------------------------------------------------------------------------
// Fused Wq/Wk/Wv transpose+convert: z in [0,48) -> head (z&15) of proj (z>>4).
// ---------------------------------------------------------------------------
__global__ __launch_bounds__(256) void transpose_qkv(
    const float* __restrict__ Wq, const float* __restrict__ Wk,
    const float* __restrict__ Wv, u16* __restrict__ dst)
{
    __shared__ float T[64][65];
    const int t = threadIdx.x;
    const int z = blockIdx.z;
    const int r0 = blockIdx.x * 64;
    const float* s = (z < 16 ? Wq : (z < 32 ? Wk : Wv)) + (size_t)(z & 15) * 65536;
    u16* d = dst + (size_t)z * 65536;
#pragma unroll
    for (int i = 0; i < 4; ++i) {
        int idx = i * 256 + t;
        int row = idx >> 4, col = (idx & 15) * 4;
        float4 v = *reinterpret_cast<const float4*>(&s[(size_t)(r0 + row) * 64 + col]);
        T[row][col] = v.x; T[row][col + 1] = v.y;
        T[row][col + 2] = v.z; T[row][col + 3] = v.w;
    }
    __syncthreads();
#pragma unroll
    for (int i = 0; i < 4; ++i) {
        int idx = i * 256 + t;
        int oc = idx >> 4, ok = (idx & 15) * 4;
        ushort4 o;
        o.x = bfu(T[ok][oc]);     o.y = bfu(T[ok + 1][oc]);
        o.z = bfu(T[ok + 2][oc]); o.w = bfu(T[ok + 3][oc]);
        *reinterpret_cast<ushort4*>(&d[(size_t)oc * 1024 + r0 + ok]) = o;
    }
}

// ---------------------------------------------------------------------------
// Generic transpose+convert (for Wo): src fp32 [R][C] -> dst bf16 [C][R].
// ---------------------------------------------------------------------------
__global__ __launch_bounds__(256) void transpose_bf16(
    const float* __restrict__ src, u16* __restrict__ dst, int R, int C)
{
    __shared__ float T[64][65];
    const int t = threadIdx.x;
    const int r0 = blockIdx.x * 64, c0 = blockIdx.y * 64;
#pragma unroll
    for (int i = 0; i < 4; ++i) {
        int idx = i * 256 + t;
        int row = idx >> 4, col = (idx & 15) * 4;
        float4 v = *reinterpret_cast<const float4*>(&src[(size_t)(r0 + row) * C + c0 + col]);
        T[row][col] = v.x; T[row][col + 1] = v.y;
        T[row][col + 2] = v.z; T[row][col + 3] = v.w;
    }
    __syncthreads();
#pragma unroll
    for (int i = 0; i < 4; ++i) {
        int idx = i * 256 + t;
        int oc = idx >> 4, ok = (idx & 15) * 4;
        ushort4 o;
        o.x = bfu(T[ok][oc]);     o.y = bfu(T[ok + 1][oc]);
        o.z = bfu(T[ok + 2][oc]); o.w = bfu(T[ok + 3][oc]);
        *reinterpret_cast<ushort4*>(&dst[(size_t)(c0 + oc) * R + r0 + ok]) = o;
    }
}

// ---------------------------------------------------------------------------
// bf16 MFMA GEMM (m97 structure, unchanged). fused=1: by -> proj/head;
// Q epilogue applies SM_SCALE. fused=0: by = n-tile, fp32 out.
// ---------------------------------------------------------------------------
__global__ __launch_bounds__(256) void gemm_mfma(
    const u16* __restrict__ A, const u16* __restrict__ Bt,
    float* __restrict__ Cf, u16* __restrict__ Cq, u16* __restrict__ Ck,
    u16* __restrict__ Cvt, int fused)
{
    __shared__ u16 As[128 * 64];
    __shared__ u16 Bs[64 * 64];

    const int tid  = threadIdx.x;
    const int lane = tid & 63;
    const int w    = tid >> 6;
    const int g    = lane >> 4;
    const int c15  = lane & 15;
    const int wr   = w >> 1, wc = w & 1;
    const int m0   = blockIdx.x * 128;
    const int by   = blockIdx.y;

    const u16* Bb = Bt + (size_t)by * (64 * 1024);
    const int srow8  = lane >> 3;
    const int schunk = lane & 7;

    f32x4 acc[4][2];
#pragma unroll
    for (int mf = 0; mf < 4; ++mf)
#pragma unroll
        for (int nf = 0; nf < 2; ++nf) acc[mf][nf] = f32x4{0.f, 0.f, 0.f, 0.f};

    for (int k0 = 0; k0 < GK; k0 += 64) {
#pragma unroll
        for (int c = 0; c < 4; ++c) {
            int row = c * 32 + w * 8 + srow8;
            int gc = schunk ^ (row & 7);
            gl_lds16(A + (size_t)(m0 + row) * GK + k0 + gc * 8,
                     As + c * 2048 + w * 512);
        }
#pragma unroll
        for (int c = 0; c < 2; ++c) {
            int row = c * 32 + w * 8 + srow8;
            int gc = schunk ^ (row & 7);
            gl_lds16(Bb + (size_t)row * GK + k0 + gc * 8,
                     Bs + c * 2048 + w * 512);
        }
        __syncthreads();

#pragma unroll
        for (int kc = 0; kc < 2; ++kc) {
            bf16x8 a[4], b[2];
#pragma unroll
            for (int mf = 0; mf < 4; ++mf) {
                int row = wr * 64 + mf * 16 + c15;
                int ch = (kc * 4 + g) ^ (row & 7);
                a[mf] = *reinterpret_cast<const bf16x8*>(As + row * 64 + ch * 8);
            }
#pragma unroll
            for (int nf = 0; nf < 2; ++nf) {
                int row = wc * 32 + nf * 16 + c15;
                int ch = (kc * 4 + g) ^ (row & 7);
                b[nf] = *reinterpret_cast<const bf16x8*>(Bs + row * 64 + ch * 8);
            }
#pragma unroll
            for (int mf = 0; mf < 4; ++mf)
#pragma unroll
                for (int nf = 0; nf < 2; ++nf)
                    acc[mf][nf] = __builtin_amdgcn_mfma_f32_16x16x32_bf16(
                        a[mf], b[nf], acc[mf][nf], 0, 0, 0);
        }
        __syncthreads();
    }

    if (!fused) {
#pragma unroll
        for (int mf = 0; mf < 4; ++mf) {
            int m = m0 + wr * 64 + mf * 16 + g * 4;
#pragma unroll
            for (int nf = 0; nf < 2; ++nf) {
                int n = by * 64 + wc * 32 + nf * 16 + c15;
#pragma unroll
                for (int r = 0; r < 4; ++r)
                    Cf[(size_t)(m + r) * 1024 + n] = acc[mf][nf][r];
            }
        }
        return;
    }
    const int proj = by >> 4;
    const int head = by & 15;
    const int b = m0 >> 11, l0 = m0 & 2047;
    if (proj < 2) {
        u16* C = proj ? Ck : Cq;
        const float qs = proj ? 1.f : SM_SCALE;
        const size_t bh = ((size_t)(b * GH + head)) * GL * 64;
#pragma unroll
        for (int mf = 0; mf < 4; ++mf) {
            int l = l0 + wr * 64 + mf * 16 + g * 4;
#pragma unroll
            for (int nf = 0; nf < 2; ++nf) {
                int n = wc * 32 + nf * 16 + c15;
#pragma unroll
                for (int r = 0; r < 4; ++r)
                    C[bh + (size_t)(l + r) * 64 + n] = bfu(acc[mf][nf][r] * qs);
            }
        }
    } else {
        const size_t bh = ((size_t)(b * GH + head)) * 64 * GL;
#pragma unroll
        for (int mf = 0; mf < 4; ++mf) {
            int l = l0 + wr * 64 + mf * 16 + g * 4;
#pragma unroll
            for (int nf = 0; nf < 2; ++nf) {
                int n = wc * 32 + nf * 16 + c15;
                ushort4 o;
                o.x = bfu(acc[mf][nf][0]); o.y = bfu(acc[mf][nf][1]);
                o.z = bfu(acc[mf][nf][2]); o.w = bfu(acc[mf][nf][3]);
                *reinterpret_cast<ushort4*>(&Cvt[bh + (size_t)n * GL + l]) = o;
            }
        }
    }
}

// ---------------------------------------------------------------------------
// One 64-k KV step, 32x32x16 MFMA, 32 q-rows per wave (swapped operands).
// K tile sigma-permuted at staging so QK^T C-regs == PV B-frag order (P stays
// in registers). Rows qi and 32+qi use swizzles ks0 and ks0^4 (full-row XOR).
// ---------------------------------------------------------------------------
template <bool DOMASK>
__device__ __forceinline__ void attn_step32(
    const u16* __restrict__ Kt, const u16* __restrict__ Vt,
    const bf16x8* qf, int qrow, int j0, int qi, int hi,
    float& m_run, float& l_run, f32x16& o0, f32x16& o1)
{
    const int ks0 = rswz(qi);
    const int ks1 = ks0 ^ 4;   // rswz(32+qi)

    // ---- S^T = K . Q^T : two stacked 32x32 tiles, d-contraction = 4 MFMA ----
    f32x16 s0 = {0.f,0.f,0.f,0.f,0.f,0.f,0.f,0.f,0.f,0.f,0.f,0.f,0.f,0.f,0.f,0.f};
    f32x16 s1 = s0;
#pragma unroll
    for (int dc = 0; dc < 4; ++dc) {
        const int x = dc * 2 + hi;
        bf16x8 kf0 = *reinterpret_cast<const bf16x8*>(Kt + qi * 64 + ((x ^ ks0) * 8));
        bf16x8 kf1 = *reinterpret_cast<const bf16x8*>(Kt + (32 + qi) * 64 + ((x ^ ks1) * 8));
        s0 = __builtin_amdgcn_mfma_f32_32x32x16_bf16(kf0, qf[dc], s0, 0, 0, 0);
        s1 = __builtin_amdgcn_mfma_f32_32x32x16_bf16(kf1, qf[dc], s1, 0, 0, 0);
    }

    // reg r of tile kt holds S for global k = j0 + 32*kt + klocal(r,hi):
    // klocal = (r&3) + 4*((r>>2)&1) + 8*hi + 16*((r>>3)&1)   [sigma mapping]
    if (DOMASK) {
#pragma unroll
        for (int r = 0; r < 16; ++r) {
            const int kl = (r & 3) + (((r >> 2) & 1) << 2) + (hi << 3)
                         + (((r >> 3) & 1) << 4);
            if (j0 + kl > qrow)      s0[r] = -__builtin_inff();
            if (j0 + 32 + kl > qrow) s1[r] = -__builtin_inff();
        }
    }

    // ---- row max: 4 chains then combine; cross-lane only xor-32 ----
    float ma = fmaxf(s0[0], s0[1]), mb = fmaxf(s0[2], s0[3]);
    float mc = fmaxf(s1[0], s1[1]), md = fmaxf(s1[2], s1[3]);
#pragma unroll
    for (int r = 4; r < 16; r += 4) {
        ma = fmaxf(ma, fmaxf(s0[r], s0[r + 1]));
        mb = fmaxf(mb, fmaxf(s0[r + 2], s0[r + 3]));
        mc = fmaxf(mc, fmaxf(s1[r], s1[r + 1]));
        md = fmaxf(md, fmaxf(s1[r + 2], s1[r + 3]));
    }
    float mx = fmaxf(fmaxf(ma, mb), fmaxf(mc, md));
    mx = fmaxf(mx, __shfl_xor(mx, 32));

    // ---- defer-max rescale (T13) ----
    if (!__all(mx <= m_run + RESCALE_THR)) {
        const float mnew = fmaxf(m_run, mx);
        const float scl  = fexp2(m_run - mnew);   // first tile: exp2(-inf)=0
        l_run *= scl;
        o0 *= scl;
        o1 *= scl;
        m_run = mnew;
    }

    // ---- exp + pack (pair p packs regs 2p,2p+1 = consecutive k) ----
    float rsum = 0.f;
    unsigned pk0[8], pk1[8];
#pragma unroll
    for (int p = 0; p < 8; ++p) {
        float a = fexp2(s0[2 * p] - m_run), b = fexp2(s0[2 * p + 1] - m_run);
        float c = fexp2(s1[2 * p] - m_run), d = fexp2(s1[2 * p + 1] - m_run);
        rsum += (a + b) + (c + d);
        pk0[p] = pack_trunc(a, b);
        pk1[p] = pack_trunc(c, d);
    }
    rsum += __shfl_xor(rsum, 32);
    l_run += rsum;

    // ---- O^T += V^T . P^T : B-frag j = packed pairs [4*(j&1)..+3] of tile j>>1
    __builtin_amdgcn_s_setprio(1);
#pragma unroll
    for (int j2 = 0; j2 < 4; ++j2) {
        const int J4 = (j2 & 1) * 4;
        uint4 uu;
        if (j2 < 2) { uu.x = pk0[J4]; uu.y = pk0[J4 + 1]; uu.z = pk0[J4 + 2]; uu.w = pk0[J4 + 3]; }
        else        { uu.x = pk1[J4]; uu.y = pk1[J4 + 1]; uu.z = pk1[J4 + 2]; uu.w = pk1[J4 + 3]; }
        bf16x8 pf = __builtin_bit_cast(bf16x8, uu);
        const int x = j2 * 2 + hi;
        bf16x8 vf0 = *reinterpret_cast<const bf16x8*>(Vt + qi * 64 + ((x ^ ks0) * 8));
        bf16x8 vf1 = *reinterpret_cast<const bf16x8*>(Vt + (32 + qi) * 64 + ((x ^ ks1) * 8));
        o0 = __builtin_amdgcn_mfma_f32_32x32x16_bf16(vf0, pf, o0, 0, 0, 0);
        o1 = __builtin_amdgcn_mfma_f32_32x32x16_bf16(vf1, pf, o1, 0, 0, 0);
    }
    __builtin_amdgcn_s_setprio(0);
}

// ---------------------------------------------------------------------------
// Causal flash attention: 512 blocks x 256 threads (4 waves x 32 q-rows =
// 128-row chunk), complementary pairing (CU sum = 36 steps uniform).
// PIPELINED staging: 3 K/V buffers, depth-2 prefetch, counted vmcnt(4) +
// raw s_barrier (no vmcnt-0 drain) -> staging overlaps compute (T3/T4).
// Per iteration i: WAIT(own tile-i landed) -> BARRIER (all waves' tile-i
// landed AND all finished compute(i-1), protecting the buffer stage(i+2)
// overwrites) -> stage(i+2) -> compute(i) -> rotate buffers.
// Tail: tile 2c masked for waves 0-1; tile 2c+1 only for waves 2-3.
// LDS 48KB -> 2 blocks/CU = 8 waves/CU.
// ---------------------------------------------------------------------------
__global__ __launch_bounds__(256) void attn_mfma(
    const u16* __restrict__ qg, const u16* __restrict__ kg,
    const u16* __restrict__ vtg, u16* __restrict__ og)
{
    __shared__ u16 Ksh[3][64 * 64];
    __shared__ u16 Vsh[3][64 * 64];

    const int tid  = threadIdx.x;
    const int lane = tid & 63;
    const int w    = tid >> 6;     // wave 0..3
    const int qi   = lane & 31;
    const int hi   = lane >> 5;

    const int bid  = blockIdx.x;
    const int j    = bid & 255;
    const int half = bid >> 8;
    const int bh   = j & 31;            // XCD = bh%8 (= bid%8): 4 heads/XCD
    const int s    = j >> 5;
    const int c    = half ? (15 - s) : s;   // 128-row chunk index, 0..15

    const size_t qkb  = (size_t)bh * GL * 64;
    const size_t vtbo = (size_t)bh * 64 * GL;

    const int qrow = c * 128 + w * 32 + qi;
    bf16x8 qf[4];
#pragma unroll
    for (int dc = 0; dc < 4; ++dc)
        qf[dc] = *reinterpret_cast<const bf16x8*>(
            qg + qkb + (size_t)qrow * 64 + dc * 16 + hi * 8);

    // staging: 4 waves cover 64 rows x 8 chunks; 2 gl_lds (K) + 2 (V) per lane.
    auto stage = [&](int t, u16* kd, u16* vd) {
#pragma unroll
        for (int c8 = 0; c8 < 2; ++c8) {
            const int row = w * 16 + c8 * 8 + (lane >> 3);   // tile row 0..63
            const int gc  = (lane & 7) ^ rswz(row);          // pre-swizzled chunk
            const int ksrc = t * 64 + (row & 32) + sig5(row & 31);
            gl_lds16(kg + qkb + (size_t)ksrc * 64 + gc * 8,
                     kd + (w * 16 + c8 * 8) * 64);
            gl_lds16(vtg + vtbo + (size_t)row * GL + t * 64 + gc * 8,
                     vd + (w * 16 + c8 * 8) * 64);
        }
    };

    float m_run = -__builtin_inff(), l_run = 0.f;
    f32x16 o0 = {0.f,0.f,0.f,0.f,0.f,0.f,0.f,0.f,0.f,0.f,0.f,0.f,0.f,0.f,0.f,0.f};
    f32x16 o1 = o0;

    const int nt = 2 * c + 2;          // KV tiles for this chunk (>= 2)
    u16 *k0 = Ksh[0], *k1 = Ksh[1], *k2 = Ksh[2];
    u16 *v0 = Vsh[0], *v1 = Vsh[1], *v2 = Vsh[2];

    stage(0, k0, v0);                  // 4 loads in flight
    stage(1, k1, v1);                  // 8 in flight

    for (int i = 0; i < nt; ++i) {
        if (i < nt - 1) WAITV4();      // own tile-i loads landed (i+1 in flight)
        else            WAITV0();      // last tile: full drain
        BARRIER();                     // all waves' tile-i landed; compute(i-1)
                                       // finished everywhere -> k2/v2 free
        if (i + 2 < nt) stage(i + 2, k2, v2);

        const int j0 = i * 64;
        if (i < 2 * c) {
            attn_step32<false>(k0, v0, qf, qrow, j0, qi, hi, m_run, l_run, o0, o1);
        } else if (i == 2 * c) {
            if (w < 2)
                attn_step32<true>(k0, v0, qf, qrow, j0, qi, hi, m_run, l_run, o0, o1);
            else
                attn_step32<false>(k0, v0, qf, qrow, j0, qi, hi, m_run, l_run, o0, o1);
        } else {                        // i == 2c+1: waves 0-1 fully masked, skip
            if (w >= 2)
                attn_step32<true>(k0, v0, qf, qrow, j0, qi, hi, m_run, l_run, o0, o1);
        }

        u16* tk = k0; k0 = k1; k1 = k2; k2 = tk;
        u16* tv = v0; v0 = v1; v1 = v2; v2 = tv;
    }

    // ---- epilogue: O[q][hd], hd = (r&3) + 8*(r>>2) + 4*hi (+32 for o1) ----
    const int b = bh >> 4, h = bh & 15;
    const float inv = 1.f / l_run;
    u16* obase = og + ((size_t)(b * GL + qrow)) * 1024 + h * 64 + 4 * hi;
#pragma unroll
    for (int rq = 0; rq < 4; ++rq) {
        ushort4 w0, w1;
        w0.x = bfu(o0[4 * rq] * inv);     w0.y = bfu(o0[4 * rq + 1] * inv);
        w0.z = bfu(o0[4 * rq + 2] * inv); w0.w = bfu(o0[4 * rq + 3] * inv);
        *reinterpret_cast<ushort4*>(obase + 8 * rq) = w0;
        w1.x = bfu(o1[4 * rq] * inv);     w1.y = bfu(o1[4 * rq + 1] * inv);
        w1.z = bfu(o1[4 * rq + 2] * inv); w1.w = bfu(o1[4 * rq + 3] * inv);
        *reinterpret_cast<ushort4*>(obase + 32 + 8 * rq) = w1;
    }
}

// ---------------------------------------------------------------------------
extern "C" void kernel_launch(void* const* d_in, const int* in_sizes, int n_in,
                              void* d_out, int out_size, void* d_ws, size_t ws_size,
                              hipStream_t stream) {
    const float* emb = (const float*)d_in[0];
    const float* Wq  = (const float*)d_in[1];
    const float* Wk  = (const float*)d_in[2];
    const float* Wv  = (const float*)d_in[3];
    const float* Wo  = (const float*)d_in[4];
    float* out = (float*)d_out;

    char* ws = (char*)d_ws;
    u16* qb   = (u16*)(ws);
    u16* kb   = (u16*)(ws + ( 8u << 20));
    u16* vtb  = (u16*)(ws + (16u << 20));
    u16* ab   = (u16*)(ws + (24u << 20));
    u16* embb = (u16*)(ws + (32u << 20));
    u16* wqt  = (u16*)(ws + (40u << 20));
    u16* wot  = (u16*)(ws + (46u << 20));

    dim3 blk(256);

    cast_bf16<<<dim3(2048), blk, 0, stream>>>(emb, embb, GM * GK / 8);
    transpose_qkv<<<dim3(16, 1, 48), blk, 0, stream>>>(Wq, Wk, Wv, wqt);
    transpose_bf16<<<dim3(16, 16, 1), blk, 0, stream>>>(Wo, wot, 1024, 1024);

    // fused Q/K/V projections (one dispatch, 48 n-slices)
    gemm_mfma<<<dim3(GM / 128, 48), blk, 0, stream>>>(
        embb, wqt, nullptr, qb, kb, vtb, 1);

    // attention: pipelined staging (3-buf, counted vmcnt, raw barrier)
    attn_mfma<<<dim3(512), blk, 0, stream>>>(qb, kb, vtb, ab);

    // output projection
    gemm_mfma<<<dim3(GM / 128, 16), blk, 0, stream>>>(
        ab, wot, out, nullptr, nullptr, nullptr, 0);
}

// Round 13
// 112.802 us; speedup vs baseline: 1.8693x; 1.0220x over previous
//
#include <hip/hip_runtime.h>
#include <hip/hip_bf16.h>

// B=2, L=2048, D=1024, H=16, HD=64.  M = B*L = 4096, K = D = 1024.
// ws (bytes):
//   qb   @ 0MB   bf16 [32][2048][64]   (Q pre-scaled by SM_SCALE)
//   kb   @ 8MB   bf16 [32][2048][64]
//   vtb  @16MB   bf16 [32][64][2048]   (V transposed)
//   ab   @24MB   bf16 [4096][1024]     (attn concat out)
//   embb @32MB   bf16 [4096][1024]
//   wqt  @40MB   bf16 [48][64][1024]   (wqt/wkt/wvt contiguous, 2MB each)
//   wot  @46MB   bf16 [1024][1024]     (Wo transposed)

#define GM 4096
#define GK 1024
#define GL 2048
#define GH 16

typedef __attribute__((ext_vector_type(8))) short bf16x8;
typedef __attribute__((ext_vector_type(4))) float f32x4;
typedef __attribute__((ext_vector_type(16))) float f32x16;
typedef unsigned short u16;

__device__ __forceinline__ u16 bfu(float x) {
    __hip_bfloat16 h = __float2bfloat16(x);
    return *reinterpret_cast<u16*>(&h);
}
__device__ __forceinline__ unsigned pack_bf16(float a, float b) {
    return ((unsigned)bfu(b) << 16) | bfu(a);
}
// truncation-pack two f32 -> {bf16(a) lo, bf16(b) hi} in one v_perm_b32
__device__ __forceinline__ unsigned pack_trunc(float a, float b) {
    return __builtin_amdgcn_perm(__float_as_uint(b), __float_as_uint(a), 0x07060302u);
}
__device__ __forceinline__ void gl_lds16(const void* g, void* l) {
    __builtin_amdgcn_global_load_lds(
        (__attribute__((address_space(1))) void*)(g),
        (__attribute__((address_space(3))) void*)(l),
        16, 0, 0);
}
__device__ __forceinline__ float fexp2(float x) {
#if __has_builtin(__builtin_amdgcn_exp2f)
    return __builtin_amdgcn_exp2f(x);
#else
    return __expf(x * 0.6931471805599453f);
#endif
}
// sigma: staged K-row p holds true kv sig5(p) (swap bits 2<->3, keep 0,1,4).
// Makes QK^T C-regs land exactly in PV B-fragment order (P in registers).
__device__ __forceinline__ int sig5(int c) {
    return (c & 3) | (((c >> 3) & 1) << 2) | (((c >> 2) & 1) << 3) | (c & 16);
}
// LDS swizzles (round-11: measured ZERO bank conflicts)
__device__ __forceinline__ int kswz(int row) { return (row & 7) ^ (row >> 3); }
__device__ __forceinline__ int vswz(int row) { return ((row & 3) ^ ((row >> 3) & 3)); }

#define WAITV0() do { asm volatile("s_waitcnt vmcnt(0)" ::: "memory"); \
                      __builtin_amdgcn_sched_barrier(0); } while (0)
// raw barrier (no compiler vmcnt drain) fenced against reordering
#define BARRIER() do { __builtin_amdgcn_sched_barrier(0); \
                       __builtin_amdgcn_s_barrier(); \
                       __builtin_amdgcn_sched_barrier(0); } while (0)

// 0.125 (1/sqrt(64)) folded with log2(e): softmax done in exp2 domain.
#define SM_SCALE 0.1803368801111204f
#define RESCALE_THR 8.0f

// ---------------------------------------------------------------------------
// fp32 -> bf16 cast, 8 elements/thread.
// ---------------------------------------------------------------------------
__global__ __launch_bounds__(256) void cast_bf16(
    const float* __restrict__ src, u16* __restrict__ dst, int n8)
{
    int i = blockIdx.x * 256 + threadIdx.x;
    if (i >= n8) return;
    float4 v0 = reinterpret_cast<const float4*>(src)[i * 2];
    float4 v1 = reinterpret_cast<const float4*>(src)[i * 2 + 1];
    uint4 o;
    o.x = pack_bf16(v0.x, v0.y);
    o.y = pack_bf16(v0.z, v0.w);
    o.z = pack_bf16(v1.x, v1.y);
    o.w = pack_bf16(v1.z, v1.w);
    reinterpret_cast<uint4*>(dst)[i] = o;
}

// ---------------------------------------------------------------------------
// Fused Wq/Wk/Wv transpose+convert: z in [0,48) -> head (z&15) of proj (z>>4).
// ---------------------------------------------------------------------------
__global__ __launch_bounds__(256) void transpose_qkv(
    const float* __restrict__ Wq, const float* __restrict__ Wk,
    const float* __restrict__ Wv, u16* __restrict__ dst)
{
    __shared__ float T[64][65];
    const int t = threadIdx.x;
    const int z = blockIdx.z;
    const int r0 = blockIdx.x * 64;
    const float* s = (z < 16 ? Wq : (z < 32 ? Wk : Wv)) + (size_t)(z & 15) * 65536;
    u16* d = dst + (size_t)z * 65536;
#pragma unroll
    for (int i = 0; i < 4; ++i) {
        int idx = i * 256 + t;
        int row = idx >> 4, col = (idx & 15) * 4;
        float4 v = *reinterpret_cast<const float4*>(&s[(size_t)(r0 + row) * 64 + col]);
        T[row][col] = v.x; T[row][col + 1] = v.y;
        T[row][col + 2] = v.z; T[row][col + 3] = v.w;
    }
    __syncthreads();
#pragma unroll
    for (int i = 0; i < 4; ++i) {
        int idx = i * 256 + t;
        int oc = idx >> 4, ok = (idx & 15) * 4;
        ushort4 o;
        o.x = bfu(T[ok][oc]);     o.y = bfu(T[ok + 1][oc]);
        o.z = bfu(T[ok + 2][oc]); o.w = bfu(T[ok + 3][oc]);
        *reinterpret_cast<ushort4*>(&d[(size_t)oc * 1024 + r0 + ok]) = o;
    }
}

// ---------------------------------------------------------------------------
// Generic transpose+convert (for Wo): src fp32 [R][C] -> dst bf16 [C][R].
// ---------------------------------------------------------------------------
__global__ __launch_bounds__(256) void transpose_bf16(
    const float* __restrict__ src, u16* __restrict__ dst, int R, int C)
{
    __shared__ float T[64][65];
    const int t = threadIdx.x;
    const int r0 = blockIdx.x * 64, c0 = blockIdx.y * 64;
#pragma unroll
    for (int i = 0; i < 4; ++i) {
        int idx = i * 256 + t;
        int row = idx >> 4, col = (idx & 15) * 4;
        float4 v = *reinterpret_cast<const float4*>(&src[(size_t)(r0 + row) * C + c0 + col]);
        T[row][col] = v.x; T[row][col + 1] = v.y;
        T[row][col + 2] = v.z; T[row][col + 3] = v.w;
    }
    __syncthreads();
#pragma unroll
    for (int i = 0; i < 4; ++i) {
        int idx = i * 256 + t;
        int oc = idx >> 4, ok = (idx & 15) * 4;
        ushort4 o;
        o.x = bfu(T[ok][oc]);     o.y = bfu(T[ok + 1][oc]);
        o.z = bfu(T[ok + 2][oc]); o.w = bfu(T[ok + 3][oc]);
        *reinterpret_cast<ushort4*>(&dst[(size_t)(c0 + oc) * R + r0 + ok]) = o;
    }
}

// ---------------------------------------------------------------------------
// bf16 MFMA GEMM (m97 structure, unchanged). fused=1: by -> proj/head;
// Q epilogue applies SM_SCALE. fused=0: by = n-tile, fp32 out.
// ---------------------------------------------------------------------------
__global__ __launch_bounds__(256) void gemm_mfma(
    const u16* __restrict__ A, const u16* __restrict__ Bt,
    float* __restrict__ Cf, u16* __restrict__ Cq, u16* __restrict__ Ck,
    u16* __restrict__ Cvt, int fused)
{
    __shared__ u16 As[128 * 64];
    __shared__ u16 Bs[64 * 64];

    const int tid  = threadIdx.x;
    const int lane = tid & 63;
    const int w    = tid >> 6;
    const int g    = lane >> 4;
    const int c15  = lane & 15;
    const int wr   = w >> 1, wc = w & 1;
    const int m0   = blockIdx.x * 128;
    const int by   = blockIdx.y;

    const u16* Bb = Bt + (size_t)by * (64 * 1024);
    const int srow8  = lane >> 3;
    const int schunk = lane & 7;

    f32x4 acc[4][2];
#pragma unroll
    for (int mf = 0; mf < 4; ++mf)
#pragma unroll
        for (int nf = 0; nf < 2; ++nf) acc[mf][nf] = f32x4{0.f, 0.f, 0.f, 0.f};

    for (int k0 = 0; k0 < GK; k0 += 64) {
#pragma unroll
        for (int c = 0; c < 4; ++c) {
            int row = c * 32 + w * 8 + srow8;
            int gc = schunk ^ (row & 7);
            gl_lds16(A + (size_t)(m0 + row) * GK + k0 + gc * 8,
                     As + c * 2048 + w * 512);
        }
#pragma unroll
        for (int c = 0; c < 2; ++c) {
            int row = c * 32 + w * 8 + srow8;
            int gc = schunk ^ (row & 7);
            gl_lds16(Bb + (size_t)row * GK + k0 + gc * 8,
                     Bs + c * 2048 + w * 512);
        }
        __syncthreads();

#pragma unroll
        for (int kc = 0; kc < 2; ++kc) {
            bf16x8 a[4], b[2];
#pragma unroll
            for (int mf = 0; mf < 4; ++mf) {
                int row = wr * 64 + mf * 16 + c15;
                int ch = (kc * 4 + g) ^ (row & 7);
                a[mf] = *reinterpret_cast<const bf16x8*>(As + row * 64 + ch * 8);
            }
#pragma unroll
            for (int nf = 0; nf < 2; ++nf) {
                int row = wc * 32 + nf * 16 + c15;
                int ch = (kc * 4 + g) ^ (row & 7);
                b[nf] = *reinterpret_cast<const bf16x8*>(Bs + row * 64 + ch * 8);
            }
#pragma unroll
            for (int mf = 0; mf < 4; ++mf)
#pragma unroll
                for (int nf = 0; nf < 2; ++nf)
                    acc[mf][nf] = __builtin_amdgcn_mfma_f32_16x16x32_bf16(
                        a[mf], b[nf], acc[mf][nf], 0, 0, 0);
        }
        __syncthreads();
    }

    if (!fused) {
#pragma unroll
        for (int mf = 0; mf < 4; ++mf) {
            int m = m0 + wr * 64 + mf * 16 + g * 4;
#pragma unroll
            for (int nf = 0; nf < 2; ++nf) {
                int n = by * 64 + wc * 32 + nf * 16 + c15;
#pragma unroll
                for (int r = 0; r < 4; ++r)
                    Cf[(size_t)(m + r) * 1024 + n] = acc[mf][nf][r];
            }
        }
        return;
    }
    const int proj = by >> 4;
    const int head = by & 15;
    const int b = m0 >> 11, l0 = m0 & 2047;
    if (proj < 2) {
        u16* C = proj ? Ck : Cq;
        const float qs = proj ? 1.f : SM_SCALE;
        const size_t bh = ((size_t)(b * GH + head)) * GL * 64;
#pragma unroll
        for (int mf = 0; mf < 4; ++mf) {
            int l = l0 + wr * 64 + mf * 16 + g * 4;
#pragma unroll
            for (int nf = 0; nf < 2; ++nf) {
                int n = wc * 32 + nf * 16 + c15;
#pragma unroll
                for (int r = 0; r < 4; ++r)
                    C[bh + (size_t)(l + r) * 64 + n] = bfu(acc[mf][nf][r] * qs);
            }
        }
    } else {
        const size_t bh = ((size_t)(b * GH + head)) * 64 * GL;
#pragma unroll
        for (int mf = 0; mf < 4; ++mf) {
            int l = l0 + wr * 64 + mf * 16 + g * 4;
#pragma unroll
            for (int nf = 0; nf < 2; ++nf) {
                int n = wc * 32 + nf * 16 + c15;
                ushort4 o;
                o.x = bfu(acc[mf][nf][0]); o.y = bfu(acc[mf][nf][1]);
                o.z = bfu(acc[mf][nf][2]); o.w = bfu(acc[mf][nf][3]);
                *reinterpret_cast<ushort4*>(&Cvt[bh + (size_t)n * GL + l]) = o;
            }
        }
    }
}

// ---------------------------------------------------------------------------
// One 32-kv step (round-11 verified core): one 32x32 S tile (4 MFMA),
// in-register P via sigma staging, PV 4 MFMA. K tile [32][64], V^T tile
// [64][32]. DM: mask tile-relative kl > qi (valid when diag aligns rh==g).
// ---------------------------------------------------------------------------
template <bool DM>
__device__ __forceinline__ void step32(
    const u16* __restrict__ Kt, const u16* __restrict__ Vt,
    const bf16x8* qf, int qi, int hi,
    float& m_run, float& l_run, f32x16& o0, f32x16& o1)
{
    const int ks = kswz(qi);

    f32x16 s = {0.f,0.f,0.f,0.f,0.f,0.f,0.f,0.f,0.f,0.f,0.f,0.f,0.f,0.f,0.f,0.f};
#pragma unroll
    for (int dc = 0; dc < 4; ++dc) {
        const int ch = (dc * 2 + hi) ^ ks;
        bf16x8 kf = *reinterpret_cast<const bf16x8*>(Kt + qi * 64 + ch * 8);
        s = __builtin_amdgcn_mfma_f32_32x32x16_bf16(kf, qf[dc], s, 0, 0, 0);
    }

    // reg r holds kv (tile-relative) = 16*(r>>3) + 8*hi + (r&7)
    if (DM) {
#pragma unroll
        for (int r = 0; r < 16; ++r) {
            const int kl = 16 * (r >> 3) + 8 * hi + (r & 7);
            if (kl > qi) s[r] = -__builtin_inff();
        }
    }

    float m01 = fmaxf(s[0], s[1]),   m23 = fmaxf(s[2], s[3]);
    float m45 = fmaxf(s[4], s[5]),   m67 = fmaxf(s[6], s[7]);
    float m89 = fmaxf(s[8], s[9]),   mab = fmaxf(s[10], s[11]);
    float mcd = fmaxf(s[12], s[13]), mef = fmaxf(s[14], s[15]);
    float mx = fmaxf(fmaxf(fmaxf(m01, m23), fmaxf(m45, m67)),
                     fmaxf(fmaxf(m89, mab), fmaxf(mcd, mef)));
    mx = fmaxf(mx, __shfl_xor(mx, 32));

    if (!__all(mx <= m_run + RESCALE_THR)) {
        const float mnew = fmaxf(m_run, mx);
        const float scl  = fexp2(m_run - mnew);   // first tile: exp2(-inf)=0
        l_run *= scl;
        o0 *= scl;
        o1 *= scl;
        m_run = mnew;
    }

    float rsum = 0.f;
    unsigned pk[8];
#pragma unroll
    for (int j = 0; j < 8; ++j) {
        float a = fexp2(s[2 * j]     - m_run);
        float b = fexp2(s[2 * j + 1] - m_run);
        rsum += a + b;
        pk[j] = pack_trunc(a, b);
    }
    rsum += __shfl_xor(rsum, 32);
    l_run += rsum;

    __builtin_amdgcn_s_setprio(1);
#pragma unroll
    for (int m = 0; m < 2; ++m) {
        uint4 uu;
        uu.x = pk[4 * m]; uu.y = pk[4 * m + 1];
        uu.z = pk[4 * m + 2]; uu.w = pk[4 * m + 3];
        bf16x8 pf = __builtin_bit_cast(bf16x8, uu);
        const int x = m * 2 + hi;
        bf16x8 vf0 = *reinterpret_cast<const bf16x8*>(
            Vt + qi * 32 + ((x ^ vswz(qi)) * 8));
        bf16x8 vf1 = *reinterpret_cast<const bf16x8*>(
            Vt + (32 + qi) * 32 + ((x ^ vswz(32 + qi)) * 8));
        o0 = __builtin_amdgcn_mfma_f32_32x32x16_bf16(vf0, pf, o0, 0, 0, 0);
        o1 = __builtin_amdgcn_mfma_f32_32x32x16_bf16(vf1, pf, o1, 0, 0, 0);
    }
    __builtin_amdgcn_s_setprio(0);
}

// ---------------------------------------------------------------------------
// Causal flash attention, 16 waves/CU: 1024 blocks x 256 thr (4 waves),
// LDS 32KB -> 4 blocks/CU (launch_bounds pins VGPR<=128 for 4 waves/SIMD).
// Block = (head, 64-row chunk c). Waves: rh=w&1 (row half), g=w>>1 (KV
// parity group: g=0 even 32-kv tiles, g=1 odd). Each group double-buffers
// its own 8KB K/V tile; WAITV0 (covered by previous compute) + raw BARRIER.
// Decode: q4=bid>>8, r=bid&255; head=(r&7)*4+q4 (4 heads/XCD), c = q4&1 ?
// 31-(r>>3) : r>>3 -> the 4 co-resident blocks/CU sum to 66 tiles uniform.
// Tail i==c: DM iff rh==g; (g=1,rh=0) fully masked -> skip (avoids inf-inf).
// Partials merged across parity groups via LDS scratch (exact fp32).
// ---------------------------------------------------------------------------
__global__ __launch_bounds__(256, 4) void attn_mfma(
    const u16* __restrict__ qg, const u16* __restrict__ kg,
    const u16* __restrict__ vtg, u16* __restrict__ og)
{
    __shared__ u16 LB[2][2][4096];   // [group][buf][K 2048 | V 2048] = 32KB

    const int tid  = threadIdx.x;
    const int lane = tid & 63;
    const int w    = tid >> 6;
    const int rh   = w & 1;
    const int g    = w >> 1;
    const int qi   = lane & 31;
    const int hi   = lane >> 5;

    const int bid = blockIdx.x;
    const int q4  = bid >> 8;
    const int r   = bid & 255;
    const int bh  = (r & 7) * 4 + q4;
    const int rr  = r >> 3;
    const int c   = (q4 & 1) ? (31 - rr) : rr;

    const size_t qkb  = (size_t)bh * GL * 64;
    const size_t vtbo = (size_t)bh * 64 * GL;

    const int qrow = c * 64 + rh * 32 + qi;
    bf16x8 qf[4];
#pragma unroll
    for (int dc = 0; dc < 4; ++dc)
        qf[dc] = *reinterpret_cast<const bf16x8*>(
            qg + qkb + (size_t)qrow * 64 + dc * 16 + hi * 8);

    // group staging: 2 waves cover K 32x64 + V^T 64x32 (8KB); 4 gl_lds/lane.
    auto stage = [&](int t, u16* kd, u16* vd) {
#pragma unroll
        for (int i = 0; i < 2; ++i) {
            const int kr  = rh * 16 + i * 8 + (lane >> 3);    // K row 0..31
            const int gck = (lane & 7) ^ kswz(kr);
            gl_lds16(kg + qkb + (size_t)(t * 32 + sig5(kr)) * 64 + gck * 8,
                     kd + (rh * 16 + i * 8) * 64);
            const int vr  = rh * 32 + i * 16 + (lane >> 2);   // V row 0..63
            const int gcv = (lane & 3) ^ vswz(vr);
            gl_lds16(vtg + vtbo + (size_t)vr * GL + t * 32 + gcv * 8,
                     vd + (rh * 32 + i * 16) * 32);
        }
    };

    float m_run = -__builtin_inff(), l_run = 0.f;
    f32x16 o0 = {0.f,0.f,0.f,0.f,0.f,0.f,0.f,0.f,0.f,0.f,0.f,0.f,0.f,0.f,0.f,0.f};
    f32x16 o1 = o0;

    stage(g, &LB[g][0][0], &LB[g][0][2048]);   // group's first tile (index g)

    for (int i = 0; i <= c; ++i) {
        WAITV0();                     // own half of tile-i landed
        BARRIER();                    // partner's half landed; prev reads done
        if (i < c)
            stage(2 * (i + 1) + g, &LB[g][(i + 1) & 1][0],
                  &LB[g][(i + 1) & 1][2048]);
        const u16* Kt = &LB[g][i & 1][0];
        const u16* Vt = &LB[g][i & 1][2048];
        if (i < c) {
            step32<false>(Kt, Vt, qf, qi, hi, m_run, l_run, o0, o1);
        } else {
            if (rh == g)
                step32<true>(Kt, Vt, qf, qi, hi, m_run, l_run, o0, o1);
            else if (g == 0)
                step32<false>(Kt, Vt, qf, qi, hi, m_run, l_run, o0, o1);
            // (g==1, rh==0): tile fully masked -> skip
        }
    }

    // ---- merge parity-group partials (exact fp32) ----
    BARRIER();
    float* scr = (float*)&LB[0][0][0];        // 17.4KB scratch overlay
    const int sidx = (rh * 64 + lane) * 34;
    if (g == 1) {
#pragma unroll
        for (int k = 0; k < 16; ++k) {
            scr[sidx + k]      = o0[k];
            scr[sidx + 16 + k] = o1[k];
        }
        scr[sidx + 32] = m_run;
        scr[sidx + 33] = l_run;
    }
    BARRIER();
    if (g == 0) {
        const float mB = scr[sidx + 32], lB = scr[sidx + 33];
        const float m  = fmaxf(m_run, mB);
        const float sA = fexp2(m_run - m);
        const float sB = fexp2(mB - m);          // mB=-inf -> 0 (empty B)
        const float inv = 1.f / (l_run * sA + lB * sB);
        const int b = bh >> 4, h = bh & 15;
        u16* obase = og + ((size_t)(b * GL + qrow)) * 1024 + h * 64 + 4 * hi;
#pragma unroll
        for (int rq = 0; rq < 4; ++rq) {
            ushort4 w0, w1;
            w0.x = bfu((o0[4*rq]   * sA + scr[sidx + 4*rq]   * sB) * inv);
            w0.y = bfu((o0[4*rq+1] * sA + scr[sidx + 4*rq+1] * sB) * inv);
            w0.z = bfu((o0[4*rq+2] * sA + scr[sidx + 4*rq+2] * sB) * inv);
            w0.w = bfu((o0[4*rq+3] * sA + scr[sidx + 4*rq+3] * sB) * inv);
            *reinterpret_cast<ushort4*>(obase + 8 * rq) = w0;
            w1.x = bfu((o1[4*rq]   * sA + scr[sidx + 16 + 4*rq]   * sB) * inv);
            w1.y = bfu((o1[4*rq+1] * sA + scr[sidx + 16 + 4*rq+1] * sB) * inv);
            w1.z = bfu((o1[4*rq+2] * sA + scr[sidx + 16 + 4*rq+2] * sB) * inv);
            w1.w = bfu((o1[4*rq+3] * sA + scr[sidx + 16 + 4*rq+3] * sB) * inv);
            *reinterpret_cast<ushort4*>(obase + 32 + 8 * rq) = w1;
        }
    }
}

// ---------------------------------------------------------------------------
extern "C" void kernel_launch(void* const* d_in, const int* in_sizes, int n_in,
                              void* d_out, int out_size, void* d_ws, size_t ws_size,
                              hipStream_t stream) {
    const float* emb = (const float*)d_in[0];
    const float* Wq  = (const float*)d_in[1];
    const float* Wk  = (const float*)d_in[2];
    const float* Wv  = (const float*)d_in[3];
    const float* Wo  = (const float*)d_in[4];
    float* out = (float*)d_out;

    char* ws = (char*)d_ws;
    u16* qb   = (u16*)(ws);
    u16* kb   = (u16*)(ws + ( 8u << 20));
    u16* vtb  = (u16*)(ws + (16u << 20));
    u16* ab   = (u16*)(ws + (24u << 20));
    u16* embb = (u16*)(ws + (32u << 20));
    u16* wqt  = (u16*)(ws + (40u << 20));
    u16* wot  = (u16*)(ws + (46u << 20));

    dim3 blk(256);

    cast_bf16<<<dim3(2048), blk, 0, stream>>>(emb, embb, GM * GK / 8);
    transpose_qkv<<<dim3(16, 1, 48), blk, 0, stream>>>(Wq, Wk, Wv, wqt);
    transpose_bf16<<<dim3(16, 16, 1), blk, 0, stream>>>(Wo, wot, 1024, 1024);

    // fused Q/K/V projections (one dispatch, 48 n-slices)
    gemm_mfma<<<dim3(GM / 128, 48), blk, 0, stream>>>(
        embb, wqt, nullptr, qb, kb, vtb, 1);

    // attention: 16 waves/CU, parity-split KV, 4 blocks/CU
    attn_mfma<<<dim3(1024), blk, 0, stream>>>(qb, kb, vtb, ab);

    // output projection
    gemm_mfma<<<dim3(GM / 128, 16), blk, 0, stream>>>(
        ab, wot, out, nullptr, nullptr, nullptr, 0);
}